// Round 4
// baseline (357.884 us; speedup 1.0000x reference)
//
#include <hip/hip_runtime.h>

// GCN forward: conv1(GEMM + sym-norm agg) -> BN -> PReLU -> conv2(GEMM + agg)
// N=100000, E=1600000, DIN=128, 2H=128, H=64. fp32 in/out.
//
// R7 changes vs R6 (352.9 us):
//  - bnstats_k fused into agg1_k: agg1 restructured to 4-wave/256-thread
//    blocks (32 nodes/block, each wave 8 nodes sequentially). Per-lane
//    register sum/sumsq across nodes -> LDS reduce across waves -> 256
//    double atomics/block into 8 interleaved bnacc copies. Removes the
//    51.2 MB z re-read pass and one dispatch.
// R6: bnstats vectorized (89 -> ~14 us). R5/R4: MFMA split-precision GEMMs,
// fused bnfinal, dinv pre-scaling, 8-deep agg unroll, NT z/out stores.

#define DIN 128
#define F1  128   // 2H
#define F2  64    // H
#define BN_EPS 1e-5f
#define NODE_BSHIFT 8          // 256 nodes per bucket
#define NODE_BMASK  255
#define CHUNK 8192             // edges per binpass block

typedef __attribute__((ext_vector_type(8))) short bf16x8;
typedef __attribute__((ext_vector_type(4))) float f32x4;
typedef __attribute__((ext_vector_type(2))) float f32x2;

__device__ __forceinline__ unsigned short f2bf(float f) {
    unsigned int u = __float_as_uint(f);
    u = u + 0x7fffu + ((u >> 16) & 1u);   // RNE
    return (unsigned short)(u >> 16);
}
__device__ __forceinline__ float bf2f(unsigned short u) { return __uint_as_float((unsigned int)u << 16); }
__device__ __forceinline__ float bf_lo(unsigned int v) { return __uint_as_float(v << 16); }
__device__ __forceinline__ float bf_hi(unsigned int v) { return __uint_as_float(v & 0xffff0000u); }

// ---------------- graph build (unchanged from R3) ----------------

__global__ __launch_bounds__(256) void hist_k(const int* __restrict__ dst,
                                              int* __restrict__ bucketcnt,
                                              int e, int nbuck) {
    __shared__ int lh[512];
    int t = threadIdx.x;
    for (int i = t; i < 512; i += 256) lh[i] = 0;
    __syncthreads();
    int base = blockIdx.x * CHUNK;
    int end = base + CHUNK; if (end > e) end = e;
    for (int i = base + t; i < end; i += 256)
        atomicAdd(&lh[dst[i] >> NODE_BSHIFT], 1);
    __syncthreads();
    for (int b = t; b < nbuck; b += 256) {
        int v = lh[b];
        if (v) atomicAdd(&bucketcnt[b], v);
    }
}

__global__ __launch_bounds__(512) void bscan_k(const int* __restrict__ bucketcnt,
                                               int* __restrict__ bucketbase,
                                               int* __restrict__ bucketcur,
                                               int* __restrict__ rowptr,
                                               int nbuck, int n, int e) {
    __shared__ int s[512];
    int t = threadIdx.x;
    int orig = (t < nbuck) ? bucketcnt[t] : 0;
    s[t] = orig;
    __syncthreads();
    int run = orig;
    for (int ofs = 1; ofs < 512; ofs <<= 1) {
        int y = (t >= ofs) ? s[t - ofs] : 0;
        __syncthreads();
        run += y;
        s[t] = run;
        __syncthreads();
    }
    if (t < nbuck) {
        int excl = run - orig;
        bucketbase[t] = excl;
        bucketcur[t] = excl;
    }
    if (t == 0) {
        bucketbase[nbuck] = e;
        rowptr[n] = e;
    }
}

__global__ __launch_bounds__(256) void binpass_k(const int* __restrict__ src,
                                                 const int* __restrict__ dst,
                                                 int* __restrict__ bucketcur,
                                                 int2* __restrict__ pairs, int e) {
    __shared__ int lh[512], lbase[512], lrank[512];
    int t = threadIdx.x;
    for (int i = t; i < 512; i += 256) { lh[i] = 0; lrank[i] = 0; }
    __syncthreads();
    int base = blockIdx.x * CHUNK;
    int end = base + CHUNK; if (end > e) end = e;
    for (int i = base + t; i < end; i += 256)
        atomicAdd(&lh[dst[i] >> NODE_BSHIFT], 1);
    __syncthreads();
    for (int b = t; b < 512; b += 256) {
        int v = lh[b];
        lbase[b] = v ? atomicAdd(&bucketcur[b], v) : 0;
    }
    __syncthreads();
    for (int i = base + t; i < end; i += 256) {
        int sv = src[i], dv = dst[i];
        int b = dv >> NODE_BSHIFT;
        int r = atomicAdd(&lrank[b], 1);
        pairs[lbase[b] + r] = make_int2(sv, dv);
    }
}

__global__ __launch_bounds__(256) void bucket_k(const int2* __restrict__ pairs,
                                                const int* __restrict__ bucketbase,
                                                float* __restrict__ dinv,
                                                int* __restrict__ rowptr,
                                                int* __restrict__ srcsorted, int n) {
    __shared__ int lh[256], loff[256], lrank[256];
    int b = blockIdx.x, t = threadIdx.x;
    int e0 = bucketbase[b], e1 = bucketbase[b + 1];
    lh[t] = 0;
    lrank[t] = 0;
    __syncthreads();
    for (int i = e0 + t; i < e1; i += 256)
        atomicAdd(&lh[pairs[i].y & NODE_BMASK], 1);
    __syncthreads();
    int deg = lh[t];
    int run = deg;
    for (int ofs = 1; ofs < 256; ofs <<= 1) {
        int y = (t >= ofs) ? lh[t - ofs] : 0;
        __syncthreads();
        run += y;
        lh[t] = run;
        __syncthreads();
    }
    loff[t] = run - deg;
    int node = (b << NODE_BSHIFT) + t;
    if (node < n) {
        dinv[node] = rsqrtf((float)(deg + 1));   // +1 self-loop
        rowptr[node] = e0 + (run - deg);
    }
    __syncthreads();
    for (int i = e0 + t; i < e1; i += 256) {
        int2 p = pairs[i];
        int lo = p.y & NODE_BMASK;
        int r = atomicAdd(&lrank[lo], 1);
        srcsorted[e0 + loff[lo] + r] = p.x;
    }
}

// ---- GEMM1 (MFMA): h'(bf16) = dinv * (x @ W1), split precision ----
// 128 rows/block, 512 threads (8 waves of 16 rows x 128 cols).

__global__ __launch_bounds__(512) void gemm1_k(const float* __restrict__ x,
                                               const float* __restrict__ W,
                                               const float* __restrict__ dinv,
                                               unsigned int* __restrict__ h, int n) {
    __shared__ unsigned short wh[128 * 128];   // W^T hi, [col][k], 16B-chunk XOR swizzle
    __shared__ unsigned short wl[128 * 128];   // W^T lo
    int t = threadIdx.x;
    // stage W1 [k=128][c=128] fp32 -> swizzled transposed bf16 hi/lo
    for (int i4 = t; i4 < 128 * 32; i4 += 512) {
        int k = i4 >> 5;
        int c0 = (i4 & 31) * 4;
        float4 v = ((const float4*)W)[i4];
        float vv[4] = {v.x, v.y, v.z, v.w};
#pragma unroll
        for (int j = 0; j < 4; j++) {
            int c = c0 + j;
            unsigned short hi = f2bf(vv[j]);
            unsigned short lo = f2bf(vv[j] - bf2f(hi));
            int addr = c * 128 + ((((k >> 3) ^ (c & 15))) << 3) + (k & 7);
            wh[addr] = hi;
            wl[addr] = lo;
        }
    }
    __syncthreads();

    int w = t >> 6, l = t & 63;
    int lr = l & 15, lg = l >> 4;
    int rowbase = blockIdx.x * 128;
    int arow = rowbase + w * 16 + lr;
    if (arow >= n) arow = n - 1;

    f32x4 acc[8];
#pragma unroll
    for (int nt = 0; nt < 8; nt++) acc[nt] = (f32x4)(0.0f);

#pragma unroll
    for (int ks = 0; ks < 4; ks++) {
        const float4* ap = (const float4*)(x + (size_t)arow * 128 + ks * 32 + lg * 8);
        float4 v0 = ap[0], v1 = ap[1];
        float vv[8] = {v0.x, v0.y, v0.z, v0.w, v1.x, v1.y, v1.z, v1.w};
        bf16x8 ah, al;
#pragma unroll
        for (int j = 0; j < 8; j++) {
            unsigned short hi = f2bf(vv[j]);
            ah[j] = (short)hi;
            al[j] = (short)f2bf(vv[j] - bf2f(hi));
        }
#pragma unroll
        for (int nt = 0; nt < 8; nt++) {
            int ao = (nt * 16 + lr) * 128 + (((4 * ks + lg) ^ lr) << 3);
            bf16x8 bh = *(const bf16x8*)&wh[ao];
            bf16x8 bl = *(const bf16x8*)&wl[ao];
            acc[nt] = __builtin_amdgcn_mfma_f32_16x16x32_bf16(ah, bh, acc[nt], 0, 0, 0);
            acc[nt] = __builtin_amdgcn_mfma_f32_16x16x32_bf16(al, bh, acc[nt], 0, 0, 0);
            acc[nt] = __builtin_amdgcn_mfma_f32_16x16x32_bf16(ah, bl, acc[nt], 0, 0, 0);
        }
    }
    __syncthreads();                       // all waves done reading W
    unsigned short* ob = wh;               // reuse as [128][128] bf16 bounce
#pragma unroll
    for (int r = 0; r < 4; r++) {
        int rl = w * 16 + lg * 4 + r;      // C row = (lane>>4)*4 + reg
        int grow = rowbase + rl;
        float di = dinv[grow < n ? grow : 0];
#pragma unroll
        for (int nt = 0; nt < 8; nt++)
            ob[rl * 128 + nt * 16 + lr] = f2bf(acc[nt][r] * di);
    }
    __syncthreads();
    const unsigned int* ob32 = (const unsigned int*)ob;
    for (int i = t; i < 128 * 64; i += 512) {
        int rl = i >> 6, cu = i & 63;
        int grow = rowbase + rl;
        if (grow < n) h[(size_t)grow * 64 + cu] = ob32[rl * 64 + cu];
    }
}

// -- aggregation 1 + fused BN stats: z = dinv_d*(sum h'_s + h'_d) + b1 --
// 256 threads = 4 waves; wave w handles 8 consecutive nodes. Per-lane
// register sum/sumsq -> LDS reduce -> 8-copy double atomics.

__global__ __launch_bounds__(256) void agg1_k(const unsigned int* __restrict__ h,  // bf16x2, 64/row
                                              const float* __restrict__ dinv,
                                              const int* __restrict__ rowptr,
                                              const int* __restrict__ srcs,
                                              const float* __restrict__ b1,
                                              float* __restrict__ z,
                                              double* __restrict__ bnacc, int n) {
    __shared__ float bsum[4][128];
    __shared__ float bsq[4][128];
    int t = threadIdx.x;
    int w = t >> 6;           // wave 0..3
    int f = t & 63;           // bf16-pair index (features 2f, 2f+1)
    float2 bb = ((const float2*)b1)[f];
    float sx = 0.f, sy = 0.f, qx = 0.f, qy = 0.f;
    int ndbase = blockIdx.x * 32 + w * 8;
#pragma unroll 1
    for (int i = 0; i < 8; i++) {
        int nd = ndbase + i;
        if (nd >= n) break;
        float di = dinv[nd];
        unsigned int sv = h[(size_t)nd * 64 + f];
        float ax = bf_lo(sv);
        float ay = bf_hi(sv);
        int e = rowptr[nd], e1 = rowptr[nd + 1];
        for (; e + 8 <= e1; e += 8) {
            int s0 = srcs[e],     s1 = srcs[e + 1], s2 = srcs[e + 2], s3 = srcs[e + 3];
            int s4 = srcs[e + 4], s5 = srcs[e + 5], s6 = srcs[e + 6], s7 = srcs[e + 7];
            unsigned int v0 = h[(size_t)s0 * 64 + f];
            unsigned int v1 = h[(size_t)s1 * 64 + f];
            unsigned int v2 = h[(size_t)s2 * 64 + f];
            unsigned int v3 = h[(size_t)s3 * 64 + f];
            unsigned int v4 = h[(size_t)s4 * 64 + f];
            unsigned int v5 = h[(size_t)s5 * 64 + f];
            unsigned int v6 = h[(size_t)s6 * 64 + f];
            unsigned int v7 = h[(size_t)s7 * 64 + f];
            ax += bf_lo(v0) + bf_lo(v1) + bf_lo(v2) + bf_lo(v3);
            ay += bf_hi(v0) + bf_hi(v1) + bf_hi(v2) + bf_hi(v3);
            ax += bf_lo(v4) + bf_lo(v5) + bf_lo(v6) + bf_lo(v7);
            ay += bf_hi(v4) + bf_hi(v5) + bf_hi(v6) + bf_hi(v7);
        }
        for (; e < e1; e++) {
            unsigned int v = h[(size_t)srcs[e] * 64 + f];
            ax += bf_lo(v);
            ay += bf_hi(v);
        }
        f32x2 o;
        o.x = fmaf(ax, di, bb.x);
        o.y = fmaf(ay, di, bb.y);
        __builtin_nontemporal_store(o, (f32x2*)z + (size_t)nd * 64 + f);
        sx += o.x; sy += o.y;
        qx = fmaf(o.x, o.x, qx);
        qy = fmaf(o.y, o.y, qy);
    }
    bsum[w][f * 2] = sx;  bsum[w][f * 2 + 1] = sy;
    bsq[w][f * 2]  = qx;  bsq[w][f * 2 + 1]  = qy;
    __syncthreads();
    if (t < 128) {
        float s = bsum[0][t] + bsum[1][t] + bsum[2][t] + bsum[3][t];
        float q = bsq[0][t] + bsq[1][t] + bsq[2][t] + bsq[3][t];
        int copy = (blockIdx.x & 7) * 256;
        atomicAdd(&bnacc[copy + t], (double)s);
        atomicAdd(&bnacc[copy + 128 + t], (double)q);
    }
}

// ---- GEMM2 (MFMA): h2'(bf16) = dinv * (prelu(bn(z)) @ W2), bnfinal fused ----
// 128 rows/block, 512 threads (8 waves of 16 rows x 64 cols).

__global__ __launch_bounds__(512) void gemm2_k(const float* __restrict__ z,
                                               const float* __restrict__ W,      // [128][64]
                                               const double* __restrict__ bnacc, // 8 copies x 256
                                               const float* __restrict__ gamma,
                                               const float* __restrict__ beta,
                                               const float* __restrict__ prelu_a,
                                               const float* __restrict__ dinv,
                                               unsigned int* __restrict__ h2, int n) {
    __shared__ unsigned short wh[64 * 128];
    __shared__ unsigned short wl[64 * 128];
    __shared__ float lsc[128], lsh[128];
    int t = threadIdx.x;
    for (int i4 = t; i4 < 128 * 16; i4 += 512) {
        int k = i4 >> 4;
        int c0 = (i4 & 15) * 4;
        float4 v = ((const float4*)W)[i4];
        float vv[4] = {v.x, v.y, v.z, v.w};
#pragma unroll
        for (int j = 0; j < 4; j++) {
            int c = c0 + j;
            unsigned short hi = f2bf(vv[j]);
            unsigned short lo = f2bf(vv[j] - bf2f(hi));
            int addr = c * 128 + ((((k >> 3) ^ (c & 15))) << 3) + (k & 7);
            wh[addr] = hi;
            wl[addr] = lo;
        }
    }
    if (t < 128) {   // fused bnfinal (sum the 8 interleaved copies)
        double sm = 0.0, qq = 0.0;
#pragma unroll
        for (int cpy = 0; cpy < 8; cpy++) {
            sm += bnacc[cpy * 256 + t];
            qq += bnacc[cpy * 256 + 128 + t];
        }
        double mean = sm / n;
        double var = qq / n - mean * mean;
        float sc = gamma[t] * rsqrtf((float)var + BN_EPS);
        lsc[t] = sc;
        lsh[t] = beta[t] - (float)mean * sc;
    }
    __syncthreads();

    float pa = prelu_a[0];
    int w = t >> 6, l = t & 63;
    int lr = l & 15, lg = l >> 4;
    int rowbase = blockIdx.x * 128;
    int arow = rowbase + w * 16 + lr;
    if (arow >= n) arow = n - 1;

    f32x4 acc[4];
#pragma unroll
    for (int nt = 0; nt < 4; nt++) acc[nt] = (f32x4)(0.0f);

#pragma unroll
    for (int ks = 0; ks < 4; ks++) {
        const float4* ap = (const float4*)(z + (size_t)arow * 128 + ks * 32 + lg * 8);
        float4 v0 = ap[0], v1 = ap[1];
        const float4* sc4 = (const float4*)&lsc[ks * 32 + lg * 8];
        const float4* sh4 = (const float4*)&lsh[ks * 32 + lg * 8];
        float4 s0 = sc4[0], s1 = sc4[1];
        float4 t0 = sh4[0], t1 = sh4[1];
        float vv[8];
        vv[0] = fmaf(v0.x, s0.x, t0.x); vv[1] = fmaf(v0.y, s0.y, t0.y);
        vv[2] = fmaf(v0.z, s0.z, t0.z); vv[3] = fmaf(v0.w, s0.w, t0.w);
        vv[4] = fmaf(v1.x, s1.x, t1.x); vv[5] = fmaf(v1.y, s1.y, t1.y);
        vv[6] = fmaf(v1.z, s1.z, t1.z); vv[7] = fmaf(v1.w, s1.w, t1.w);
        bf16x8 ah, al;
#pragma unroll
        for (int j = 0; j < 8; j++) {
            float y = vv[j] >= 0.f ? vv[j] : pa * vv[j];
            unsigned short hi = f2bf(y);
            ah[j] = (short)hi;
            al[j] = (short)f2bf(y - bf2f(hi));
        }
#pragma unroll
        for (int nt = 0; nt < 4; nt++) {
            int ao = (nt * 16 + lr) * 128 + (((4 * ks + lg) ^ lr) << 3);
            bf16x8 bh = *(const bf16x8*)&wh[ao];
            bf16x8 bl = *(const bf16x8*)&wl[ao];
            acc[nt] = __builtin_amdgcn_mfma_f32_16x16x32_bf16(ah, bh, acc[nt], 0, 0, 0);
            acc[nt] = __builtin_amdgcn_mfma_f32_16x16x32_bf16(al, bh, acc[nt], 0, 0, 0);
            acc[nt] = __builtin_amdgcn_mfma_f32_16x16x32_bf16(ah, bl, acc[nt], 0, 0, 0);
        }
    }
    __syncthreads();
    unsigned short* ob = wh;   // reuse as [128][64] bf16 bounce
#pragma unroll
    for (int r = 0; r < 4; r++) {
        int rl = w * 16 + lg * 4 + r;
        int grow = rowbase + rl;
        float di = dinv[grow < n ? grow : 0];
#pragma unroll
        for (int nt = 0; nt < 4; nt++)
            ob[rl * 64 + nt * 16 + lr] = f2bf(acc[nt][r] * di);
    }
    __syncthreads();
    const unsigned int* ob32 = (const unsigned int*)ob;
    for (int i = t; i < 128 * 32; i += 512) {
        int rl = i >> 5, cu = i & 31;
        int grow = rowbase + rl;
        if (grow < n) h2[(size_t)grow * 32 + cu] = ob32[rl * 32 + cu];
    }
}

// ------------ aggregation 2 -> output (bf16 gather, fp32 out) ------------

__global__ __launch_bounds__(64) void agg2_k(const unsigned short* __restrict__ hs,  // bf16, 64/row
                                             const float* __restrict__ dinv,
                                             const int* __restrict__ rowptr,
                                             const int* __restrict__ srcs,
                                             const float* __restrict__ b2,
                                             float* __restrict__ out, int n) {
    int nd = blockIdx.x;
    int f = threadIdx.x;
    float di = dinv[nd];
    float acc = bf2f(hs[(size_t)nd * F2 + f]);
    int e = rowptr[nd], e1 = rowptr[nd + 1];
    for (; e + 8 <= e1; e += 8) {
        int s0 = srcs[e],     s1 = srcs[e + 1], s2 = srcs[e + 2], s3 = srcs[e + 3];
        int s4 = srcs[e + 4], s5 = srcs[e + 5], s6 = srcs[e + 6], s7 = srcs[e + 7];
        float h0 = bf2f(hs[(size_t)s0 * F2 + f]);
        float h1 = bf2f(hs[(size_t)s1 * F2 + f]);
        float h2 = bf2f(hs[(size_t)s2 * F2 + f]);
        float h3 = bf2f(hs[(size_t)s3 * F2 + f]);
        float h4 = bf2f(hs[(size_t)s4 * F2 + f]);
        float h5 = bf2f(hs[(size_t)s5 * F2 + f]);
        float h6 = bf2f(hs[(size_t)s6 * F2 + f]);
        float h7 = bf2f(hs[(size_t)s7 * F2 + f]);
        acc += h0 + h1 + h2 + h3;
        acc += h4 + h5 + h6 + h7;
    }
    for (; e < e1; e++)
        acc += bf2f(hs[(size_t)srcs[e] * F2 + f]);
    float o = fmaf(acc, di, b2[f]);
    __builtin_nontemporal_store(o, out + (size_t)nd * F2 + f);
}

// ---------------- launch ----------------

extern "C" void kernel_launch(void* const* d_in, const int* in_sizes, int n_in,
                              void* d_out, int out_size, void* d_ws, size_t ws_size,
                              hipStream_t stream) {
    const float* x       = (const float*)d_in[0];
    const int*   ei      = (const int*)d_in[1];
    const float* W1      = (const float*)d_in[2];
    const float* b1      = (const float*)d_in[3];
    const float* W2      = (const float*)d_in[4];
    const float* b2      = (const float*)d_in[5];
    const float* gamma   = (const float*)d_in[6];
    const float* beta    = (const float*)d_in[7];
    const float* prelu_a = (const float*)d_in[8];

    const int N = in_sizes[0] / DIN;
    const int E = in_sizes[1] / 2;
    const int* src = ei;
    const int* dst = ei + E;
    const int NBUCK = (N + NODE_BMASK) >> NODE_BSHIFT;  // 391 for N=100000

    char* p = (char*)d_ws;
    size_t off = 0;
    auto take = [&](size_t bytes) -> char* {
        char* r = p + off;
        off = (off + bytes + 255) & ~(size_t)255;
        return r;
    };
    int*            bucketcnt  = (int*)take(512 * 4);
    int*            bucketbase = (int*)take(513 * 4);
    int*            bucketcur  = (int*)take(512 * 4);
    float*          dinv       = (float*)take((size_t)N * 4);
    int*            rowptr     = (int*)take((size_t)(N + 1) * 4);
    int*            srcsorted  = (int*)take((size_t)E * 4);
    int2*           pairs      = (int2*)take((size_t)E * 8);
    double*         bnacc      = (double*)take(8 * 256 * 8);   // 8 interleaved copies
    unsigned int*   h          = (unsigned int*)take((size_t)N * 64 * 4);  // bf16 h' (128 feats)
    float*          z          = (float*)take((size_t)N * F1 * 4);
    unsigned int*   h2         = h;   // h dead after agg1; bf16 h2' (64 feats)
    float*          out        = (float*)d_out;

    hipMemsetAsync(bucketcnt, 0, 512 * 4, stream);
    hipMemsetAsync(bnacc, 0, 8 * 256 * 8, stream);

    const int eb = (E + CHUNK - 1) / CHUNK;

    hist_k<<<eb, 256, 0, stream>>>(dst, bucketcnt, E, NBUCK);
    bscan_k<<<1, 512, 0, stream>>>(bucketcnt, bucketbase, bucketcur, rowptr, NBUCK, N, E);
    binpass_k<<<eb, 256, 0, stream>>>(src, dst, bucketcur, pairs, E);
    bucket_k<<<NBUCK, 256, 0, stream>>>(pairs, bucketbase, dinv, rowptr, srcsorted, N);

    gemm1_k<<<(N + 127) / 128, 512, 0, stream>>>(x, W1, dinv, h, N);
    agg1_k<<<(N + 31) / 32, 256, 0, stream>>>(h, dinv, rowptr, srcsorted, b1, z, bnacc, N);
    gemm2_k<<<(N + 127) / 128, 512, 0, stream>>>(z, W2, bnacc, gamma, beta, prelu_a, dinv, h2, N);
    agg2_k<<<N, F2, 0, stream>>>((const unsigned short*)h2, dinv, rowptr, srcsorted, b2, out, N);
}

// Round 5
// 342.419 us; speedup vs baseline: 1.0452x; 1.0452x over previous
//
#include <hip/hip_runtime.h>

// GCN forward: conv1(GEMM + sym-norm agg) -> BN -> PReLU -> conv2(GEMM + agg)
// N=100000, E=1600000, DIN=128, 2H=128, H=64. fp32 in/out.
//
// R8 changes vs R7 (357.9, regression) / R6 (352.9):
//  - REVERT R7's agg1/bnstats fusion (cost +22 us in agg1: wave count 100k->12.5k,
//    tail imbalance). Back to 1-wave-per-node agg + separate R6 bnstats.
//  - agg1/agg2: dual-edge gather. Lanes 0-31 gather edge e (uint2/uint per
//    lane), lanes 32-63 edge e+1 -> half the gather instructions, 2x edges in
//    flight. Self-loop as virtual edge v=0; halves merged via shfl_xor(32).
//  - wprep_k: W1/W2 pre-converted once to swizzled transposed bf16 hi/lo in
//    global (96 KB, L2-hot). gemm staging becomes a linear conflict-free
//    uint4 copy (was ~8-way-conflicted 2B ds_writes + f2bf VALU per block).

#define DIN 128
#define F1  128   // 2H
#define F2  64    // H
#define BN_EPS 1e-5f
#define NODE_BSHIFT 8          // 256 nodes per bucket
#define NODE_BMASK  255
#define CHUNK 8192             // edges per binpass block

typedef __attribute__((ext_vector_type(8))) short bf16x8;
typedef __attribute__((ext_vector_type(8))) unsigned short u16x8;
typedef __attribute__((ext_vector_type(4))) float f32x4;
typedef __attribute__((ext_vector_type(2))) float f32x2;

__device__ __forceinline__ unsigned short f2bf(float f) {
    unsigned int u = __float_as_uint(f);
    u = u + 0x7fffu + ((u >> 16) & 1u);   // RNE
    return (unsigned short)(u >> 16);
}
__device__ __forceinline__ float bf2f(unsigned short u) { return __uint_as_float((unsigned int)u << 16); }
__device__ __forceinline__ float bf_lo(unsigned int v) { return __uint_as_float(v << 16); }
__device__ __forceinline__ float bf_hi(unsigned int v) { return __uint_as_float(v & 0xffff0000u); }

// ---------------- graph build (unchanged) ----------------

__global__ __launch_bounds__(256) void hist_k(const int* __restrict__ dst,
                                              int* __restrict__ bucketcnt,
                                              int e, int nbuck) {
    __shared__ int lh[512];
    int t = threadIdx.x;
    for (int i = t; i < 512; i += 256) lh[i] = 0;
    __syncthreads();
    int base = blockIdx.x * CHUNK;
    int end = base + CHUNK; if (end > e) end = e;
    for (int i = base + t; i < end; i += 256)
        atomicAdd(&lh[dst[i] >> NODE_BSHIFT], 1);
    __syncthreads();
    for (int b = t; b < nbuck; b += 256) {
        int v = lh[b];
        if (v) atomicAdd(&bucketcnt[b], v);
    }
}

__global__ __launch_bounds__(512) void bscan_k(const int* __restrict__ bucketcnt,
                                               int* __restrict__ bucketbase,
                                               int* __restrict__ bucketcur,
                                               int* __restrict__ rowptr,
                                               int nbuck, int n, int e) {
    __shared__ int s[512];
    int t = threadIdx.x;
    int orig = (t < nbuck) ? bucketcnt[t] : 0;
    s[t] = orig;
    __syncthreads();
    int run = orig;
    for (int ofs = 1; ofs < 512; ofs <<= 1) {
        int y = (t >= ofs) ? s[t - ofs] : 0;
        __syncthreads();
        run += y;
        s[t] = run;
        __syncthreads();
    }
    if (t < nbuck) {
        int excl = run - orig;
        bucketbase[t] = excl;
        bucketcur[t] = excl;
    }
    if (t == 0) {
        bucketbase[nbuck] = e;
        rowptr[n] = e;
    }
}

__global__ __launch_bounds__(256) void binpass_k(const int* __restrict__ src,
                                                 const int* __restrict__ dst,
                                                 int* __restrict__ bucketcur,
                                                 int2* __restrict__ pairs, int e) {
    __shared__ int lh[512], lbase[512], lrank[512];
    int t = threadIdx.x;
    for (int i = t; i < 512; i += 256) { lh[i] = 0; lrank[i] = 0; }
    __syncthreads();
    int base = blockIdx.x * CHUNK;
    int end = base + CHUNK; if (end > e) end = e;
    for (int i = base + t; i < end; i += 256)
        atomicAdd(&lh[dst[i] >> NODE_BSHIFT], 1);
    __syncthreads();
    for (int b = t; b < 512; b += 256) {
        int v = lh[b];
        lbase[b] = v ? atomicAdd(&bucketcur[b], v) : 0;
    }
    __syncthreads();
    for (int i = base + t; i < end; i += 256) {
        int sv = src[i], dv = dst[i];
        int b = dv >> NODE_BSHIFT;
        int r = atomicAdd(&lrank[b], 1);
        pairs[lbase[b] + r] = make_int2(sv, dv);
    }
}

__global__ __launch_bounds__(256) void bucket_k(const int2* __restrict__ pairs,
                                                const int* __restrict__ bucketbase,
                                                float* __restrict__ dinv,
                                                int* __restrict__ rowptr,
                                                int* __restrict__ srcsorted, int n) {
    __shared__ int lh[256], loff[256], lrank[256];
    int b = blockIdx.x, t = threadIdx.x;
    int e0 = bucketbase[b], e1 = bucketbase[b + 1];
    lh[t] = 0;
    lrank[t] = 0;
    __syncthreads();
    for (int i = e0 + t; i < e1; i += 256)
        atomicAdd(&lh[pairs[i].y & NODE_BMASK], 1);
    __syncthreads();
    int deg = lh[t];
    int run = deg;
    for (int ofs = 1; ofs < 256; ofs <<= 1) {
        int y = (t >= ofs) ? lh[t - ofs] : 0;
        __syncthreads();
        run += y;
        lh[t] = run;
        __syncthreads();
    }
    loff[t] = run - deg;
    int node = (b << NODE_BSHIFT) + t;
    if (node < n) {
        dinv[node] = rsqrtf((float)(deg + 1));   // +1 self-loop
        rowptr[node] = e0 + (run - deg);
    }
    __syncthreads();
    for (int i = e0 + t; i < e1; i += 256) {
        int2 p = pairs[i];
        int lo = p.y & NODE_BMASK;
        int r = atomicAdd(&lrank[lo], 1);
        srcsorted[e0 + loff[lo] + r] = p.x;
    }
}

// ---- W pre-conversion: fp32 [k][c] -> swizzled transposed bf16 hi/lo ----
// addr(c,k) = c*128 + ((k>>3)^(c&15))*8 + (k&7)   (ushort units)

__global__ __launch_bounds__(256) void wprep_k(const float* __restrict__ W1,
                                               const float* __restrict__ W2,
                                               unsigned short* __restrict__ wt1h,
                                               unsigned short* __restrict__ wt1l,
                                               unsigned short* __restrict__ wt2h,
                                               unsigned short* __restrict__ wt2l) {
    int t = blockIdx.x * 256 + threadIdx.x;
    if (t < 2048) {                 // W1: 128 cols x 16 k-octets
        int c = t >> 4, k8 = (t & 15) * 8;
        u16x8 hv, lv;
#pragma unroll
        for (int j = 0; j < 8; j++) {
            float v = W1[(size_t)(k8 + j) * 128 + c];
            unsigned short hi = f2bf(v);
            hv[j] = hi;
            lv[j] = f2bf(v - bf2f(hi));
        }
        int addr = c * 128 + (((k8 >> 3) ^ (c & 15)) << 3);
        *(u16x8*)&wt1h[addr] = hv;
        *(u16x8*)&wt1l[addr] = lv;
    } else if (t < 3072) {          // W2: 64 cols x 16 k-octets
        int tt = t - 2048;
        int c = tt >> 4, k8 = (tt & 15) * 8;
        u16x8 hv, lv;
#pragma unroll
        for (int j = 0; j < 8; j++) {
            float v = W2[(size_t)(k8 + j) * 64 + c];
            unsigned short hi = f2bf(v);
            hv[j] = hi;
            lv[j] = f2bf(v - bf2f(hi));
        }
        int addr = c * 128 + (((k8 >> 3) ^ (c & 15)) << 3);
        *(u16x8*)&wt2h[addr] = hv;
        *(u16x8*)&wt2l[addr] = lv;
    }
}

// ---- GEMM1 (MFMA): h'(bf16) = dinv * (x @ W1), split precision ----
// 128 rows/block, 512 threads (8 waves of 16 rows x 128 cols).

__global__ __launch_bounds__(512) void gemm1_k(const float* __restrict__ x,
                                               const unsigned short* __restrict__ wt1h,
                                               const unsigned short* __restrict__ wt1l,
                                               const float* __restrict__ dinv,
                                               unsigned int* __restrict__ h, int n) {
    __shared__ unsigned short wh[128 * 128];   // W^T hi, swizzled (prebuilt layout)
    __shared__ unsigned short wl[128 * 128];   // W^T lo
    int t = threadIdx.x;
    {   // linear conflict-free staging copy (L2-hot source)
        const uint4* gh = (const uint4*)wt1h;
        const uint4* gl = (const uint4*)wt1l;
        uint4* dh = (uint4*)wh;
        uint4* dl = (uint4*)wl;
        for (int i = t; i < 2048; i += 512) { dh[i] = gh[i]; dl[i] = gl[i]; }
    }
    __syncthreads();

    int w = t >> 6, l = t & 63;
    int lr = l & 15, lg = l >> 4;
    int rowbase = blockIdx.x * 128;
    int arow = rowbase + w * 16 + lr;
    if (arow >= n) arow = n - 1;

    f32x4 acc[8];
#pragma unroll
    for (int nt = 0; nt < 8; nt++) acc[nt] = (f32x4)(0.0f);

#pragma unroll
    for (int ks = 0; ks < 4; ks++) {
        const float4* ap = (const float4*)(x + (size_t)arow * 128 + ks * 32 + lg * 8);
        float4 v0 = ap[0], v1 = ap[1];
        float vv[8] = {v0.x, v0.y, v0.z, v0.w, v1.x, v1.y, v1.z, v1.w};
        bf16x8 ah, al;
#pragma unroll
        for (int j = 0; j < 8; j++) {
            unsigned short hi = f2bf(vv[j]);
            ah[j] = (short)hi;
            al[j] = (short)f2bf(vv[j] - bf2f(hi));
        }
#pragma unroll
        for (int nt = 0; nt < 8; nt++) {
            int ao = (nt * 16 + lr) * 128 + (((4 * ks + lg) ^ lr) << 3);
            bf16x8 bh = *(const bf16x8*)&wh[ao];
            bf16x8 bl = *(const bf16x8*)&wl[ao];
            acc[nt] = __builtin_amdgcn_mfma_f32_16x16x32_bf16(ah, bh, acc[nt], 0, 0, 0);
            acc[nt] = __builtin_amdgcn_mfma_f32_16x16x32_bf16(al, bh, acc[nt], 0, 0, 0);
            acc[nt] = __builtin_amdgcn_mfma_f32_16x16x32_bf16(ah, bl, acc[nt], 0, 0, 0);
        }
    }
    __syncthreads();                       // all waves done reading W
    unsigned short* ob = wh;               // reuse as [128][128] bf16 bounce
#pragma unroll
    for (int r = 0; r < 4; r++) {
        int rl = w * 16 + lg * 4 + r;      // C row = (lane>>4)*4 + reg
        int grow = rowbase + rl;
        float di = dinv[grow < n ? grow : 0];
#pragma unroll
        for (int nt = 0; nt < 8; nt++)
            ob[rl * 128 + nt * 16 + lr] = f2bf(acc[nt][r] * di);
    }
    __syncthreads();
    const unsigned int* ob32 = (const unsigned int*)ob;
    for (int i = t; i < 128 * 64; i += 512) {
        int rl = i >> 6, cu = i & 63;
        int grow = rowbase + rl;
        if (grow < n) h[(size_t)grow * 64 + cu] = ob32[rl * 64 + cu];
    }
}

// -------- aggregation 1: z = dinv_d * (sum h'_s + h'_d) + b1 --------
// 1 wave/node; lanes 0-31 gather even virtual edges, 32-63 odd (uint2/lane).
// Virtual edge v=0 is the self-loop. Halves merged via shfl_xor(32).

__global__ __launch_bounds__(64) void agg1_k(const unsigned int* __restrict__ h,  // bf16x2, 64/row
                                             const float* __restrict__ dinv,
                                             const int* __restrict__ rowptr,
                                             const int* __restrict__ srcs,
                                             const float* __restrict__ b1,
                                             float* __restrict__ z, int n) {
    int nd = blockIdx.x;
    int l = threadIdx.x;
    int half = l >> 5;
    int q = l & 31;                       // uint2 index: feats 4q..4q+3
    const uint2* hrow = (const uint2*)h;  // 32 uint2 per row
    float di = dinv[nd];
    float a0 = 0.f, a1 = 0.f, a2 = 0.f, a3 = 0.f;
    int e0 = rowptr[nd];
    int cnt = rowptr[nd + 1] - e0 + 1;    // +1 virtual self edge
    int v = half;
    if (v < cnt) {
        int s = (v == 0) ? nd : srcs[e0 + v - 1];
        uint2 u = hrow[(size_t)s * 32 + q];
        a0 += bf_lo(u.x); a1 += bf_hi(u.x); a2 += bf_lo(u.y); a3 += bf_hi(u.y);
    }
    v += 2;
    for (; v + 14 < cnt; v += 16) {
        int i0 = e0 + v - 1;
        int s0 = srcs[i0],      s1 = srcs[i0 + 2],  s2 = srcs[i0 + 4],  s3 = srcs[i0 + 6];
        int s4 = srcs[i0 + 8],  s5 = srcs[i0 + 10], s6 = srcs[i0 + 12], s7 = srcs[i0 + 14];
        uint2 u0 = hrow[(size_t)s0 * 32 + q];
        uint2 u1 = hrow[(size_t)s1 * 32 + q];
        uint2 u2 = hrow[(size_t)s2 * 32 + q];
        uint2 u3 = hrow[(size_t)s3 * 32 + q];
        uint2 u4 = hrow[(size_t)s4 * 32 + q];
        uint2 u5 = hrow[(size_t)s5 * 32 + q];
        uint2 u6 = hrow[(size_t)s6 * 32 + q];
        uint2 u7 = hrow[(size_t)s7 * 32 + q];
        a0 += bf_lo(u0.x) + bf_lo(u1.x) + bf_lo(u2.x) + bf_lo(u3.x);
        a1 += bf_hi(u0.x) + bf_hi(u1.x) + bf_hi(u2.x) + bf_hi(u3.x);
        a2 += bf_lo(u0.y) + bf_lo(u1.y) + bf_lo(u2.y) + bf_lo(u3.y);
        a3 += bf_hi(u0.y) + bf_hi(u1.y) + bf_hi(u2.y) + bf_hi(u3.y);
        a0 += bf_lo(u4.x) + bf_lo(u5.x) + bf_lo(u6.x) + bf_lo(u7.x);
        a1 += bf_hi(u4.x) + bf_hi(u5.x) + bf_hi(u6.x) + bf_hi(u7.x);
        a2 += bf_lo(u4.y) + bf_lo(u5.y) + bf_lo(u6.y) + bf_lo(u7.y);
        a3 += bf_hi(u4.y) + bf_hi(u5.y) + bf_hi(u6.y) + bf_hi(u7.y);
    }
    for (; v + 6 < cnt; v += 8) {
        int i0 = e0 + v - 1;
        int s0 = srcs[i0], s1 = srcs[i0 + 2], s2 = srcs[i0 + 4], s3 = srcs[i0 + 6];
        uint2 u0 = hrow[(size_t)s0 * 32 + q];
        uint2 u1 = hrow[(size_t)s1 * 32 + q];
        uint2 u2 = hrow[(size_t)s2 * 32 + q];
        uint2 u3 = hrow[(size_t)s3 * 32 + q];
        a0 += bf_lo(u0.x) + bf_lo(u1.x) + bf_lo(u2.x) + bf_lo(u3.x);
        a1 += bf_hi(u0.x) + bf_hi(u1.x) + bf_hi(u2.x) + bf_hi(u3.x);
        a2 += bf_lo(u0.y) + bf_lo(u1.y) + bf_lo(u2.y) + bf_lo(u3.y);
        a3 += bf_hi(u0.y) + bf_hi(u1.y) + bf_hi(u2.y) + bf_hi(u3.y);
    }
    for (; v < cnt; v += 2) {
        int s = srcs[e0 + v - 1];
        uint2 u = hrow[(size_t)s * 32 + q];
        a0 += bf_lo(u.x); a1 += bf_hi(u.x); a2 += bf_lo(u.y); a3 += bf_hi(u.y);
    }
    a0 += __shfl_xor(a0, 32);
    a1 += __shfl_xor(a1, 32);
    a2 += __shfl_xor(a2, 32);
    a3 += __shfl_xor(a3, 32);
    if (half == 0) {
        float4 bb = ((const float4*)b1)[q];
        f32x4 o;
        o.x = fmaf(a0, di, bb.x);
        o.y = fmaf(a1, di, bb.y);
        o.z = fmaf(a2, di, bb.z);
        o.w = fmaf(a3, di, bb.w);
        __builtin_nontemporal_store(o, (f32x4*)z + (size_t)nd * 32 + q);
    }
}

// ---------------- BatchNorm stats (R6 form) ----------------

__global__ __launch_bounds__(256) void bnstats_k(const float* __restrict__ z,
                                                 double* __restrict__ bnacc, int n) {
    __shared__ float reds[8][128];
    __shared__ float redq[8][128];
    int t = threadIdx.x;
    int q = t >> 5;          // row lane 0..7
    int c = t & 31;          // float4 column
    const float4* z4 = (const float4*)z;
    float4 s = make_float4(0.f, 0.f, 0.f, 0.f);
    float4 sq = make_float4(0.f, 0.f, 0.f, 0.f);
    int stride = gridDim.x * 8;
#pragma unroll 2
    for (int r = blockIdx.x * 8 + q; r < n; r += stride) {
        float4 v = z4[(size_t)r * 32 + c];
        s.x += v.x; s.y += v.y; s.z += v.z; s.w += v.w;
        sq.x = fmaf(v.x, v.x, sq.x);
        sq.y = fmaf(v.y, v.y, sq.y);
        sq.z = fmaf(v.z, v.z, sq.z);
        sq.w = fmaf(v.w, v.w, sq.w);
    }
    *(float4*)&reds[q][c * 4] = s;
    *(float4*)&redq[q][c * 4] = sq;
    __syncthreads();
    if (t < 128) {
        float ssum = 0.f, qsum = 0.f;
#pragma unroll
        for (int i = 0; i < 8; i++) {
            ssum += reds[i][t];
            qsum += redq[i][t];
        }
        int copy = (blockIdx.x & 3) * 256;
        atomicAdd(&bnacc[copy + t], (double)ssum);
        atomicAdd(&bnacc[copy + 128 + t], (double)qsum);
    }
}

// ---- GEMM2 (MFMA): h2'(bf16) = dinv * (prelu(bn(z)) @ W2), bnfinal fused ----

__global__ __launch_bounds__(512) void gemm2_k(const float* __restrict__ z,
                                               const unsigned short* __restrict__ wt2h,
                                               const unsigned short* __restrict__ wt2l,
                                               const double* __restrict__ bnacc, // 4 copies x 256
                                               const float* __restrict__ gamma,
                                               const float* __restrict__ beta,
                                               const float* __restrict__ prelu_a,
                                               const float* __restrict__ dinv,
                                               unsigned int* __restrict__ h2, int n) {
    __shared__ unsigned short wh[64 * 128];
    __shared__ unsigned short wl[64 * 128];
    __shared__ float lsc[128], lsh[128];
    int t = threadIdx.x;
    {   // linear conflict-free staging copy
        const uint4* gh = (const uint4*)wt2h;
        const uint4* gl = (const uint4*)wt2l;
        uint4* dh = (uint4*)wh;
        uint4* dl = (uint4*)wl;
        for (int i = t; i < 1024; i += 512) { dh[i] = gh[i]; dl[i] = gl[i]; }
    }
    if (t < 128) {   // fused bnfinal (sum the 4 interleaved copies)
        double sm = 0.0, qq = 0.0;
#pragma unroll
        for (int cpy = 0; cpy < 4; cpy++) {
            sm += bnacc[cpy * 256 + t];
            qq += bnacc[cpy * 256 + 128 + t];
        }
        double mean = sm / n;
        double var = qq / n - mean * mean;
        float sc = gamma[t] * rsqrtf((float)var + BN_EPS);
        lsc[t] = sc;
        lsh[t] = beta[t] - (float)mean * sc;
    }
    __syncthreads();

    float pa = prelu_a[0];
    int w = t >> 6, l = t & 63;
    int lr = l & 15, lg = l >> 4;
    int rowbase = blockIdx.x * 128;
    int arow = rowbase + w * 16 + lr;
    if (arow >= n) arow = n - 1;

    f32x4 acc[4];
#pragma unroll
    for (int nt = 0; nt < 4; nt++) acc[nt] = (f32x4)(0.0f);

#pragma unroll
    for (int ks = 0; ks < 4; ks++) {
        const float4* ap = (const float4*)(z + (size_t)arow * 128 + ks * 32 + lg * 8);
        float4 v0 = ap[0], v1 = ap[1];
        const float4* sc4 = (const float4*)&lsc[ks * 32 + lg * 8];
        const float4* sh4 = (const float4*)&lsh[ks * 32 + lg * 8];
        float4 s0 = sc4[0], s1 = sc4[1];
        float4 t0 = sh4[0], t1 = sh4[1];
        float vv[8];
        vv[0] = fmaf(v0.x, s0.x, t0.x); vv[1] = fmaf(v0.y, s0.y, t0.y);
        vv[2] = fmaf(v0.z, s0.z, t0.z); vv[3] = fmaf(v0.w, s0.w, t0.w);
        vv[4] = fmaf(v1.x, s1.x, t1.x); vv[5] = fmaf(v1.y, s1.y, t1.y);
        vv[6] = fmaf(v1.z, s1.z, t1.z); vv[7] = fmaf(v1.w, s1.w, t1.w);
        bf16x8 ah, al;
#pragma unroll
        for (int j = 0; j < 8; j++) {
            float y = vv[j] >= 0.f ? vv[j] : pa * vv[j];
            unsigned short hi = f2bf(y);
            ah[j] = (short)hi;
            al[j] = (short)f2bf(y - bf2f(hi));
        }
#pragma unroll
        for (int nt = 0; nt < 4; nt++) {
            int ao = (nt * 16 + lr) * 128 + (((4 * ks + lg) ^ lr) << 3);
            bf16x8 bh = *(const bf16x8*)&wh[ao];
            bf16x8 bl = *(const bf16x8*)&wl[ao];
            acc[nt] = __builtin_amdgcn_mfma_f32_16x16x32_bf16(ah, bh, acc[nt], 0, 0, 0);
            acc[nt] = __builtin_amdgcn_mfma_f32_16x16x32_bf16(al, bh, acc[nt], 0, 0, 0);
            acc[nt] = __builtin_amdgcn_mfma_f32_16x16x32_bf16(ah, bl, acc[nt], 0, 0, 0);
        }
    }
    __syncthreads();
    unsigned short* ob = wh;   // reuse as [128][64] bf16 bounce
#pragma unroll
    for (int r = 0; r < 4; r++) {
        int rl = w * 16 + lg * 4 + r;
        int grow = rowbase + rl;
        float di = dinv[grow < n ? grow : 0];
#pragma unroll
        for (int nt = 0; nt < 4; nt++)
            ob[rl * 64 + nt * 16 + lr] = f2bf(acc[nt][r] * di);
    }
    __syncthreads();
    const unsigned int* ob32 = (const unsigned int*)ob;
    for (int i = t; i < 128 * 32; i += 512) {
        int rl = i >> 5, cu = i & 31;
        int grow = rowbase + rl;
        if (grow < n) h2[(size_t)grow * 32 + cu] = ob32[rl * 32 + cu];
    }
}

// ------------ aggregation 2 -> output (dual-edge bf16 gather) ------------

__global__ __launch_bounds__(64) void agg2_k(const unsigned int* __restrict__ hs,  // bf16x2, 32/row
                                             const float* __restrict__ dinv,
                                             const int* __restrict__ rowptr,
                                             const int* __restrict__ srcs,
                                             const float* __restrict__ b2,
                                             float* __restrict__ out, int n) {
    int nd = blockIdx.x;
    int l = threadIdx.x;
    int half = l >> 5;
    int q = l & 31;                       // uint index: feats 2q, 2q+1
    float di = dinv[nd];
    float a0 = 0.f, a1 = 0.f;
    int e0 = rowptr[nd];
    int cnt = rowptr[nd + 1] - e0 + 1;    // +1 virtual self edge
    int v = half;
    if (v < cnt) {
        int s = (v == 0) ? nd : srcs[e0 + v - 1];
        unsigned int u = hs[(size_t)s * 32 + q];
        a0 += bf_lo(u); a1 += bf_hi(u);
    }
    v += 2;
    for (; v + 14 < cnt; v += 16) {
        int i0 = e0 + v - 1;
        int s0 = srcs[i0],      s1 = srcs[i0 + 2],  s2 = srcs[i0 + 4],  s3 = srcs[i0 + 6];
        int s4 = srcs[i0 + 8],  s5 = srcs[i0 + 10], s6 = srcs[i0 + 12], s7 = srcs[i0 + 14];
        unsigned int u0 = hs[(size_t)s0 * 32 + q];
        unsigned int u1 = hs[(size_t)s1 * 32 + q];
        unsigned int u2 = hs[(size_t)s2 * 32 + q];
        unsigned int u3 = hs[(size_t)s3 * 32 + q];
        unsigned int u4 = hs[(size_t)s4 * 32 + q];
        unsigned int u5 = hs[(size_t)s5 * 32 + q];
        unsigned int u6 = hs[(size_t)s6 * 32 + q];
        unsigned int u7 = hs[(size_t)s7 * 32 + q];
        a0 += bf_lo(u0) + bf_lo(u1) + bf_lo(u2) + bf_lo(u3);
        a1 += bf_hi(u0) + bf_hi(u1) + bf_hi(u2) + bf_hi(u3);
        a0 += bf_lo(u4) + bf_lo(u5) + bf_lo(u6) + bf_lo(u7);
        a1 += bf_hi(u4) + bf_hi(u5) + bf_hi(u6) + bf_hi(u7);
    }
    for (; v + 6 < cnt; v += 8) {
        int i0 = e0 + v - 1;
        int s0 = srcs[i0], s1 = srcs[i0 + 2], s2 = srcs[i0 + 4], s3 = srcs[i0 + 6];
        unsigned int u0 = hs[(size_t)s0 * 32 + q];
        unsigned int u1 = hs[(size_t)s1 * 32 + q];
        unsigned int u2 = hs[(size_t)s2 * 32 + q];
        unsigned int u3 = hs[(size_t)s3 * 32 + q];
        a0 += bf_lo(u0) + bf_lo(u1) + bf_lo(u2) + bf_lo(u3);
        a1 += bf_hi(u0) + bf_hi(u1) + bf_hi(u2) + bf_hi(u3);
    }
    for (; v < cnt; v += 2) {
        int s = srcs[e0 + v - 1];
        unsigned int u = hs[(size_t)s * 32 + q];
        a0 += bf_lo(u); a1 += bf_hi(u);
    }
    a0 += __shfl_xor(a0, 32);
    a1 += __shfl_xor(a1, 32);
    if (half == 0) {
        float2 bb = ((const float2*)b2)[q];
        f32x2 o;
        o.x = fmaf(a0, di, bb.x);
        o.y = fmaf(a1, di, bb.y);
        __builtin_nontemporal_store(o, (f32x2*)out + (size_t)nd * 32 + q);
    }
}

// ---------------- launch ----------------

extern "C" void kernel_launch(void* const* d_in, const int* in_sizes, int n_in,
                              void* d_out, int out_size, void* d_ws, size_t ws_size,
                              hipStream_t stream) {
    const float* x       = (const float*)d_in[0];
    const int*   ei      = (const int*)d_in[1];
    const float* W1      = (const float*)d_in[2];
    const float* b1      = (const float*)d_in[3];
    const float* W2      = (const float*)d_in[4];
    const float* b2      = (const float*)d_in[5];
    const float* gamma   = (const float*)d_in[6];
    const float* beta    = (const float*)d_in[7];
    const float* prelu_a = (const float*)d_in[8];

    const int N = in_sizes[0] / DIN;
    const int E = in_sizes[1] / 2;
    const int* src = ei;
    const int* dst = ei + E;
    const int NBUCK = (N + NODE_BMASK) >> NODE_BSHIFT;  // 391 for N=100000

    char* p = (char*)d_ws;
    size_t off = 0;
    auto take = [&](size_t bytes) -> char* {
        char* r = p + off;
        off = (off + bytes + 255) & ~(size_t)255;
        return r;
    };
    int*            bucketcnt  = (int*)take(512 * 4);
    int*            bucketbase = (int*)take(513 * 4);
    int*            bucketcur  = (int*)take(512 * 4);
    float*          dinv       = (float*)take((size_t)N * 4);
    int*            rowptr     = (int*)take((size_t)(N + 1) * 4);
    int*            srcsorted  = (int*)take((size_t)E * 4);
    int2*           pairs      = (int2*)take((size_t)E * 8);
    double*         bnacc      = (double*)take(4 * 256 * 8);   // 4 interleaved copies
    unsigned short* wt1h       = (unsigned short*)take(128 * 128 * 2);
    unsigned short* wt1l       = (unsigned short*)take(128 * 128 * 2);
    unsigned short* wt2h       = (unsigned short*)take(64 * 128 * 2);
    unsigned short* wt2l       = (unsigned short*)take(64 * 128 * 2);
    unsigned int*   h          = (unsigned int*)take((size_t)N * 64 * 4);  // bf16 h' (128 feats)
    float*          z          = (float*)take((size_t)N * F1 * 4);
    unsigned int*   h2         = h;   // h dead after agg1; bf16 h2' (64 feats)
    float*          out        = (float*)d_out;

    hipMemsetAsync(bucketcnt, 0, 512 * 4, stream);
    hipMemsetAsync(bnacc, 0, 4 * 256 * 8, stream);

    const int eb = (E + CHUNK - 1) / CHUNK;

    wprep_k<<<12, 256, 0, stream>>>(W1, W2, wt1h, wt1l, wt2h, wt2l);
    hist_k<<<eb, 256, 0, stream>>>(dst, bucketcnt, E, NBUCK);
    bscan_k<<<1, 512, 0, stream>>>(bucketcnt, bucketbase, bucketcur, rowptr, NBUCK, N, E);
    binpass_k<<<eb, 256, 0, stream>>>(src, dst, bucketcur, pairs, E);
    bucket_k<<<NBUCK, 256, 0, stream>>>(pairs, bucketbase, dinv, rowptr, srcsorted, N);

    gemm1_k<<<(N + 127) / 128, 512, 0, stream>>>(x, wt1h, wt1l, dinv, h, N);
    agg1_k<<<N, 64, 0, stream>>>(h, dinv, rowptr, srcsorted, b1, z, N);
    bnstats_k<<<1024, 256, 0, stream>>>(z, bnacc, N);
    gemm2_k<<<(N + 127) / 128, 512, 0, stream>>>(z, wt2h, wt2l, bnacc, gamma, beta, prelu_a, dinv, h2, N);
    agg2_k<<<N, F2, 0, stream>>>((const unsigned int*)h2, dinv, rowptr, srcsorted, b2, out, N);
}

// Round 6
// 312.050 us; speedup vs baseline: 1.1469x; 1.0973x over previous
//
#include <hip/hip_runtime.h>

// GCN forward: conv1(GEMM + sym-norm agg) -> BN -> PReLU -> conv2(GEMM + agg)
// N=100000, E=1600000, DIN=128, 2H=128, H=64. fp32 in/out.
//
// R9 changes vs R8 (342.4):
//  - REVERT R8's dual-edge agg (cost +5 us, VALU 17->32%). Back to R6 shape
//    (64 lanes x 4B/lane full-row gather), now with 16-deep gather batches
//    (srcs prefetched into regs; tiers 16/8/4/1) for more loads in flight.
//  - Graph build: hist_k + bscan_k removed. Padded buckets (PADB=4608/bucket):
//    bucketcur preinit to b*PADB in wprep_k, binpass reserves via one atomic
//    per (block,bucket), bucket_k derives extent from bucketcur and writes
//    rowptr/rowend per node. 2 fewer dispatches, no 1-block scan serialization.
// R8 keepers: wprep'd swizzled bf16 hi/lo W tables (linear LDS staging),
// MFMA split-precision GEMMs, fused bnfinal, dinv pre-scaling, NT stores.

#define DIN 128
#define F1  128   // 2H
#define F2  64    // H
#define BN_EPS 1e-5f
#define NODE_BSHIFT 8          // 256 nodes per bucket
#define NODE_BMASK  255
#define CHUNK 8192             // edges per binpass block
#define PADB 4608              // padded edges per bucket (mean 4096 + 8 sigma)

typedef __attribute__((ext_vector_type(8))) short bf16x8;
typedef __attribute__((ext_vector_type(8))) unsigned short u16x8;
typedef __attribute__((ext_vector_type(4))) float f32x4;
typedef __attribute__((ext_vector_type(2))) float f32x2;

__device__ __forceinline__ unsigned short f2bf(float f) {
    unsigned int u = __float_as_uint(f);
    u = u + 0x7fffu + ((u >> 16) & 1u);   // RNE
    return (unsigned short)(u >> 16);
}
__device__ __forceinline__ float bf2f(unsigned short u) { return __uint_as_float((unsigned int)u << 16); }
__device__ __forceinline__ float bf_lo(unsigned int v) { return __uint_as_float(v << 16); }
__device__ __forceinline__ float bf_hi(unsigned int v) { return __uint_as_float(v & 0xffff0000u); }

// ---- W pre-conversion + bucketcur init ----
// addr(c,k) = c*128 + ((k>>3)^(c&15))*8 + (k&7)   (ushort units)

__global__ __launch_bounds__(256) void wprep_k(const float* __restrict__ W1,
                                               const float* __restrict__ W2,
                                               unsigned short* __restrict__ wt1h,
                                               unsigned short* __restrict__ wt1l,
                                               unsigned short* __restrict__ wt2h,
                                               unsigned short* __restrict__ wt2l,
                                               int* __restrict__ bucketcur) {
    int t = blockIdx.x * 256 + threadIdx.x;
    if (t < 2048) {                 // W1: 128 cols x 16 k-octets
        int c = t >> 4, k8 = (t & 15) * 8;
        u16x8 hv, lv;
#pragma unroll
        for (int j = 0; j < 8; j++) {
            float v = W1[(size_t)(k8 + j) * 128 + c];
            unsigned short hi = f2bf(v);
            hv[j] = hi;
            lv[j] = f2bf(v - bf2f(hi));
        }
        int addr = c * 128 + (((k8 >> 3) ^ (c & 15)) << 3);
        *(u16x8*)&wt1h[addr] = hv;
        *(u16x8*)&wt1l[addr] = lv;
    } else if (t < 3072) {          // W2: 64 cols x 16 k-octets
        int tt = t - 2048;
        int c = tt >> 4, k8 = (tt & 15) * 8;
        u16x8 hv, lv;
#pragma unroll
        for (int j = 0; j < 8; j++) {
            float v = W2[(size_t)(k8 + j) * 64 + c];
            unsigned short hi = f2bf(v);
            hv[j] = hi;
            lv[j] = f2bf(v - bf2f(hi));
        }
        int addr = c * 128 + (((k8 >> 3) ^ (c & 15)) << 3);
        *(u16x8*)&wt2h[addr] = hv;
        *(u16x8*)&wt2l[addr] = lv;
    } else if (t < 3584) {          // bucketcur init
        int b = t - 3072;
        bucketcur[b] = b * PADB;
    }
}

// ---------------- graph build ----------------
// block counting-sort of 8192-edge chunks into padded per-bucket regions.

__global__ __launch_bounds__(256) void binpass_k(const int* __restrict__ src,
                                                 const int* __restrict__ dst,
                                                 int* __restrict__ bucketcur,
                                                 int2* __restrict__ pairs, int e) {
    __shared__ int lh[512], lbase[512], lrank[512];
    int t = threadIdx.x;
    for (int i = t; i < 512; i += 256) { lh[i] = 0; lrank[i] = 0; }
    __syncthreads();
    int base = blockIdx.x * CHUNK;
    int end = base + CHUNK; if (end > e) end = e;
    for (int i = base + t; i < end; i += 256)
        atomicAdd(&lh[dst[i] >> NODE_BSHIFT], 1);
    __syncthreads();
    for (int b = t; b < 512; b += 256) {
        int v = lh[b];
        lbase[b] = v ? atomicAdd(&bucketcur[b], v) : 0;
    }
    __syncthreads();
    for (int i = base + t; i < end; i += 256) {
        int sv = src[i], dv = dst[i];
        int b = dv >> NODE_BSHIFT;
        int r = atomicAdd(&lrank[b], 1);
        int idx = lbase[b] + r;
        if (idx < (b + 1) * PADB) pairs[idx] = make_int2(sv, dv);
    }
}

// one block per bucket: per-node degree -> dinv + rowptr/rowend, fine scatter.

__global__ __launch_bounds__(256) void bucket_k(const int2* __restrict__ pairs,
                                                const int* __restrict__ bucketcur,
                                                float* __restrict__ dinv,
                                                int* __restrict__ rowptr,
                                                int* __restrict__ rowend,
                                                int* __restrict__ srcsorted, int n) {
    __shared__ int lh[256], loff[256], lrank[256];
    int b = blockIdx.x, t = threadIdx.x;
    int e0 = b * PADB;
    int e1 = bucketcur[b];
    lh[t] = 0;
    lrank[t] = 0;
    __syncthreads();
    for (int i = e0 + t; i < e1; i += 256)
        atomicAdd(&lh[pairs[i].y & NODE_BMASK], 1);
    __syncthreads();
    int deg = lh[t];
    int run = deg;
    for (int ofs = 1; ofs < 256; ofs <<= 1) {
        int y = (t >= ofs) ? lh[t - ofs] : 0;
        __syncthreads();
        run += y;
        lh[t] = run;
        __syncthreads();
    }
    loff[t] = run - deg;
    int node = (b << NODE_BSHIFT) + t;
    if (node < n) {
        dinv[node] = rsqrtf((float)(deg + 1));   // +1 self-loop
        rowptr[node] = e0 + (run - deg);
        rowend[node] = e0 + run;
    }
    __syncthreads();
    for (int i = e0 + t; i < e1; i += 256) {
        int2 p = pairs[i];
        int lo = p.y & NODE_BMASK;
        int r = atomicAdd(&lrank[lo], 1);
        srcsorted[e0 + loff[lo] + r] = p.x;
    }
}

// ---- GEMM1 (MFMA): h'(bf16) = dinv * (x @ W1), split precision ----
// 128 rows/block, 512 threads (8 waves of 16 rows x 128 cols).

__global__ __launch_bounds__(512) void gemm1_k(const float* __restrict__ x,
                                               const unsigned short* __restrict__ wt1h,
                                               const unsigned short* __restrict__ wt1l,
                                               const float* __restrict__ dinv,
                                               unsigned int* __restrict__ h, int n) {
    __shared__ unsigned short wh[128 * 128];   // W^T hi, swizzled (prebuilt layout)
    __shared__ unsigned short wl[128 * 128];   // W^T lo
    int t = threadIdx.x;
    {   // linear conflict-free staging copy (L2-hot source)
        const uint4* gh = (const uint4*)wt1h;
        const uint4* gl = (const uint4*)wt1l;
        uint4* dh = (uint4*)wh;
        uint4* dl = (uint4*)wl;
        for (int i = t; i < 2048; i += 512) { dh[i] = gh[i]; dl[i] = gl[i]; }
    }
    __syncthreads();

    int w = t >> 6, l = t & 63;
    int lr = l & 15, lg = l >> 4;
    int rowbase = blockIdx.x * 128;
    int arow = rowbase + w * 16 + lr;
    if (arow >= n) arow = n - 1;

    f32x4 acc[8];
#pragma unroll
    for (int nt = 0; nt < 8; nt++) acc[nt] = (f32x4)(0.0f);

#pragma unroll
    for (int ks = 0; ks < 4; ks++) {
        const float4* ap = (const float4*)(x + (size_t)arow * 128 + ks * 32 + lg * 8);
        float4 v0 = ap[0], v1 = ap[1];
        float vv[8] = {v0.x, v0.y, v0.z, v0.w, v1.x, v1.y, v1.z, v1.w};
        bf16x8 ah, al;
#pragma unroll
        for (int j = 0; j < 8; j++) {
            unsigned short hi = f2bf(vv[j]);
            ah[j] = (short)hi;
            al[j] = (short)f2bf(vv[j] - bf2f(hi));
        }
#pragma unroll
        for (int nt = 0; nt < 8; nt++) {
            int ao = (nt * 16 + lr) * 128 + (((4 * ks + lg) ^ lr) << 3);
            bf16x8 bh = *(const bf16x8*)&wh[ao];
            bf16x8 bl = *(const bf16x8*)&wl[ao];
            acc[nt] = __builtin_amdgcn_mfma_f32_16x16x32_bf16(ah, bh, acc[nt], 0, 0, 0);
            acc[nt] = __builtin_amdgcn_mfma_f32_16x16x32_bf16(al, bh, acc[nt], 0, 0, 0);
            acc[nt] = __builtin_amdgcn_mfma_f32_16x16x32_bf16(ah, bl, acc[nt], 0, 0, 0);
        }
    }
    __syncthreads();                       // all waves done reading W
    unsigned short* ob = wh;               // reuse as [128][128] bf16 bounce
#pragma unroll
    for (int r = 0; r < 4; r++) {
        int rl = w * 16 + lg * 4 + r;      // C row = (lane>>4)*4 + reg
        int grow = rowbase + rl;
        float di = dinv[grow < n ? grow : 0];
#pragma unroll
        for (int nt = 0; nt < 8; nt++)
            ob[rl * 128 + nt * 16 + lr] = f2bf(acc[nt][r] * di);
    }
    __syncthreads();
    const unsigned int* ob32 = (const unsigned int*)ob;
    for (int i = t; i < 128 * 64; i += 512) {
        int rl = i >> 6, cu = i & 63;
        int grow = rowbase + rl;
        if (grow < n) h[(size_t)grow * 64 + cu] = ob32[rl * 64 + cu];
    }
}

// -------- aggregation 1: z = dinv_d * (sum h'_s + h'_d) + b1 --------
// 1 wave/node, 64 lanes x 4B/lane row gather; 16-deep batched gathers.

__global__ __launch_bounds__(64) void agg1_k(const unsigned int* __restrict__ h,  // bf16x2, 64/row
                                             const float* __restrict__ dinv,
                                             const int* __restrict__ rowptr,
                                             const int* __restrict__ rowend,
                                             const int* __restrict__ srcs,
                                             const float* __restrict__ b1,
                                             float* __restrict__ z, int n) {
    int nd = blockIdx.x;
    int f = threadIdx.x;  // bf16-pair index, 0..63
    float di = dinv[nd];
    unsigned int sv = h[(size_t)nd * 64 + f];
    float ax = bf_lo(sv);
    float ay = bf_hi(sv);
    int e = rowptr[nd], e1 = rowend[nd];
    for (; e + 16 <= e1; e += 16) {
        int s[16];
#pragma unroll
        for (int j = 0; j < 16; j++) s[j] = srcs[e + j];
        unsigned int v[16];
#pragma unroll
        for (int j = 0; j < 16; j++) v[j] = h[(size_t)s[j] * 64 + f];
#pragma unroll
        for (int j = 0; j < 16; j++) { ax += bf_lo(v[j]); ay += bf_hi(v[j]); }
    }
    for (; e + 8 <= e1; e += 8) {
        int s[8];
#pragma unroll
        for (int j = 0; j < 8; j++) s[j] = srcs[e + j];
        unsigned int v[8];
#pragma unroll
        for (int j = 0; j < 8; j++) v[j] = h[(size_t)s[j] * 64 + f];
#pragma unroll
        for (int j = 0; j < 8; j++) { ax += bf_lo(v[j]); ay += bf_hi(v[j]); }
    }
    for (; e + 4 <= e1; e += 4) {
        int s[4];
#pragma unroll
        for (int j = 0; j < 4; j++) s[j] = srcs[e + j];
        unsigned int v[4];
#pragma unroll
        for (int j = 0; j < 4; j++) v[j] = h[(size_t)s[j] * 64 + f];
#pragma unroll
        for (int j = 0; j < 4; j++) { ax += bf_lo(v[j]); ay += bf_hi(v[j]); }
    }
    for (; e < e1; e++) {
        unsigned int v = h[(size_t)srcs[e] * 64 + f];
        ax += bf_lo(v);
        ay += bf_hi(v);
    }
    float2 bb = ((const float2*)b1)[f];
    f32x2 o;
    o.x = fmaf(ax, di, bb.x);
    o.y = fmaf(ay, di, bb.y);
    __builtin_nontemporal_store(o, (f32x2*)z + (size_t)nd * 64 + f);
}

// ---------------- BatchNorm stats ----------------

__global__ __launch_bounds__(256) void bnstats_k(const float* __restrict__ z,
                                                 double* __restrict__ bnacc, int n) {
    __shared__ float reds[8][128];
    __shared__ float redq[8][128];
    int t = threadIdx.x;
    int q = t >> 5;          // row lane 0..7
    int c = t & 31;          // float4 column
    const float4* z4 = (const float4*)z;
    float4 s = make_float4(0.f, 0.f, 0.f, 0.f);
    float4 sq = make_float4(0.f, 0.f, 0.f, 0.f);
    int stride = gridDim.x * 8;
#pragma unroll 2
    for (int r = blockIdx.x * 8 + q; r < n; r += stride) {
        float4 v = z4[(size_t)r * 32 + c];
        s.x += v.x; s.y += v.y; s.z += v.z; s.w += v.w;
        sq.x = fmaf(v.x, v.x, sq.x);
        sq.y = fmaf(v.y, v.y, sq.y);
        sq.z = fmaf(v.z, v.z, sq.z);
        sq.w = fmaf(v.w, v.w, sq.w);
    }
    *(float4*)&reds[q][c * 4] = s;
    *(float4*)&redq[q][c * 4] = sq;
    __syncthreads();
    if (t < 128) {
        float ssum = 0.f, qsum = 0.f;
#pragma unroll
        for (int i = 0; i < 8; i++) {
            ssum += reds[i][t];
            qsum += redq[i][t];
        }
        int copy = (blockIdx.x & 3) * 256;
        atomicAdd(&bnacc[copy + t], (double)ssum);
        atomicAdd(&bnacc[copy + 128 + t], (double)qsum);
    }
}

// ---- GEMM2 (MFMA): h2'(bf16) = dinv * (prelu(bn(z)) @ W2), bnfinal fused ----

__global__ __launch_bounds__(512) void gemm2_k(const float* __restrict__ z,
                                               const unsigned short* __restrict__ wt2h,
                                               const unsigned short* __restrict__ wt2l,
                                               const double* __restrict__ bnacc, // 4 copies x 256
                                               const float* __restrict__ gamma,
                                               const float* __restrict__ beta,
                                               const float* __restrict__ prelu_a,
                                               const float* __restrict__ dinv,
                                               unsigned int* __restrict__ h2, int n) {
    __shared__ unsigned short wh[64 * 128];
    __shared__ unsigned short wl[64 * 128];
    __shared__ float lsc[128], lsh[128];
    int t = threadIdx.x;
    {   // linear conflict-free staging copy
        const uint4* gh = (const uint4*)wt2h;
        const uint4* gl = (const uint4*)wt2l;
        uint4* dh = (uint4*)wh;
        uint4* dl = (uint4*)wl;
        for (int i = t; i < 1024; i += 512) { dh[i] = gh[i]; dl[i] = gl[i]; }
    }
    if (t < 128) {   // fused bnfinal (sum the 4 interleaved copies)
        double sm = 0.0, qq = 0.0;
#pragma unroll
        for (int cpy = 0; cpy < 4; cpy++) {
            sm += bnacc[cpy * 256 + t];
            qq += bnacc[cpy * 256 + 128 + t];
        }
        double mean = sm / n;
        double var = qq / n - mean * mean;
        float sc = gamma[t] * rsqrtf((float)var + BN_EPS);
        lsc[t] = sc;
        lsh[t] = beta[t] - (float)mean * sc;
    }
    __syncthreads();

    float pa = prelu_a[0];
    int w = t >> 6, l = t & 63;
    int lr = l & 15, lg = l >> 4;
    int rowbase = blockIdx.x * 128;
    int arow = rowbase + w * 16 + lr;
    if (arow >= n) arow = n - 1;

    f32x4 acc[4];
#pragma unroll
    for (int nt = 0; nt < 4; nt++) acc[nt] = (f32x4)(0.0f);

#pragma unroll
    for (int ks = 0; ks < 4; ks++) {
        const float4* ap = (const float4*)(z + (size_t)arow * 128 + ks * 32 + lg * 8);
        float4 v0 = ap[0], v1 = ap[1];
        const float4* sc4 = (const float4*)&lsc[ks * 32 + lg * 8];
        const float4* sh4 = (const float4*)&lsh[ks * 32 + lg * 8];
        float4 s0 = sc4[0], s1 = sc4[1];
        float4 t0 = sh4[0], t1 = sh4[1];
        float vv[8];
        vv[0] = fmaf(v0.x, s0.x, t0.x); vv[1] = fmaf(v0.y, s0.y, t0.y);
        vv[2] = fmaf(v0.z, s0.z, t0.z); vv[3] = fmaf(v0.w, s0.w, t0.w);
        vv[4] = fmaf(v1.x, s1.x, t1.x); vv[5] = fmaf(v1.y, s1.y, t1.y);
        vv[6] = fmaf(v1.z, s1.z, t1.z); vv[7] = fmaf(v1.w, s1.w, t1.w);
        bf16x8 ah, al;
#pragma unroll
        for (int j = 0; j < 8; j++) {
            float y = vv[j] >= 0.f ? vv[j] : pa * vv[j];
            unsigned short hi = f2bf(y);
            ah[j] = (short)hi;
            al[j] = (short)f2bf(y - bf2f(hi));
        }
#pragma unroll
        for (int nt = 0; nt < 4; nt++) {
            int ao = (nt * 16 + lr) * 128 + (((4 * ks + lg) ^ lr) << 3);
            bf16x8 bh = *(const bf16x8*)&wh[ao];
            bf16x8 bl = *(const bf16x8*)&wl[ao];
            acc[nt] = __builtin_amdgcn_mfma_f32_16x16x32_bf16(ah, bh, acc[nt], 0, 0, 0);
            acc[nt] = __builtin_amdgcn_mfma_f32_16x16x32_bf16(al, bh, acc[nt], 0, 0, 0);
            acc[nt] = __builtin_amdgcn_mfma_f32_16x16x32_bf16(ah, bl, acc[nt], 0, 0, 0);
        }
    }
    __syncthreads();
    unsigned short* ob = wh;   // reuse as [128][64] bf16 bounce
#pragma unroll
    for (int r = 0; r < 4; r++) {
        int rl = w * 16 + lg * 4 + r;
        int grow = rowbase + rl;
        float di = dinv[grow < n ? grow : 0];
#pragma unroll
        for (int nt = 0; nt < 4; nt++)
            ob[rl * 64 + nt * 16 + lr] = f2bf(acc[nt][r] * di);
    }
    __syncthreads();
    const unsigned int* ob32 = (const unsigned int*)ob;
    for (int i = t; i < 128 * 32; i += 512) {
        int rl = i >> 5, cu = i & 31;
        int grow = rowbase + rl;
        if (grow < n) h2[(size_t)grow * 32 + cu] = ob32[rl * 32 + cu];
    }
}

// ------------ aggregation 2 -> output (bf16 gather, fp32 out) ------------
// 1 wave/node, 64 lanes x 2B/lane row gather; 16-deep batched gathers.

__global__ __launch_bounds__(64) void agg2_k(const unsigned short* __restrict__ hs,  // bf16, 64/row
                                             const float* __restrict__ dinv,
                                             const int* __restrict__ rowptr,
                                             const int* __restrict__ rowend,
                                             const int* __restrict__ srcs,
                                             const float* __restrict__ b2,
                                             float* __restrict__ out, int n) {
    int nd = blockIdx.x;
    int f = threadIdx.x;
    float di = dinv[nd];
    float acc = bf2f(hs[(size_t)nd * F2 + f]);
    int e = rowptr[nd], e1 = rowend[nd];
    for (; e + 16 <= e1; e += 16) {
        int s[16];
#pragma unroll
        for (int j = 0; j < 16; j++) s[j] = srcs[e + j];
        unsigned short v[16];
#pragma unroll
        for (int j = 0; j < 16; j++) v[j] = hs[(size_t)s[j] * F2 + f];
#pragma unroll
        for (int j = 0; j < 16; j++) acc += bf2f(v[j]);
    }
    for (; e + 8 <= e1; e += 8) {
        int s[8];
#pragma unroll
        for (int j = 0; j < 8; j++) s[j] = srcs[e + j];
        unsigned short v[8];
#pragma unroll
        for (int j = 0; j < 8; j++) v[j] = hs[(size_t)s[j] * F2 + f];
#pragma unroll
        for (int j = 0; j < 8; j++) acc += bf2f(v[j]);
    }
    for (; e + 4 <= e1; e += 4) {
        int s[4];
#pragma unroll
        for (int j = 0; j < 4; j++) s[j] = srcs[e + j];
        unsigned short v[4];
#pragma unroll
        for (int j = 0; j < 4; j++) v[j] = hs[(size_t)s[j] * F2 + f];
#pragma unroll
        for (int j = 0; j < 4; j++) acc += bf2f(v[j]);
    }
    for (; e < e1; e++)
        acc += bf2f(hs[(size_t)srcs[e] * F2 + f]);
    float o = fmaf(acc, di, b2[f]);
    __builtin_nontemporal_store(o, out + (size_t)nd * F2 + f);
}

// ---------------- launch ----------------

extern "C" void kernel_launch(void* const* d_in, const int* in_sizes, int n_in,
                              void* d_out, int out_size, void* d_ws, size_t ws_size,
                              hipStream_t stream) {
    const float* x       = (const float*)d_in[0];
    const int*   ei      = (const int*)d_in[1];
    const float* W1      = (const float*)d_in[2];
    const float* b1      = (const float*)d_in[3];
    const float* W2      = (const float*)d_in[4];
    const float* b2      = (const float*)d_in[5];
    const float* gamma   = (const float*)d_in[6];
    const float* beta    = (const float*)d_in[7];
    const float* prelu_a = (const float*)d_in[8];

    const int N = in_sizes[0] / DIN;
    const int E = in_sizes[1] / 2;
    const int* src = ei;
    const int* dst = ei + E;
    const int NBUCK = (N + NODE_BMASK) >> NODE_BSHIFT;  // 391 for N=100000

    char* p = (char*)d_ws;
    size_t off = 0;
    auto take = [&](size_t bytes) -> char* {
        char* r = p + off;
        off = (off + bytes + 255) & ~(size_t)255;
        return r;
    };
    int*            bucketcur  = (int*)take(512 * 4);
    float*          dinv       = (float*)take((size_t)N * 4);
    int*            rowptr     = (int*)take((size_t)N * 4);
    int*            rowend     = (int*)take((size_t)N * 4);
    int*            srcsorted  = (int*)take((size_t)512 * PADB * 4);
    int2*           pairs      = (int2*)take((size_t)512 * PADB * 8);
    double*         bnacc      = (double*)take(4 * 256 * 8);   // 4 interleaved copies
    unsigned short* wt1h       = (unsigned short*)take(128 * 128 * 2);
    unsigned short* wt1l       = (unsigned short*)take(128 * 128 * 2);
    unsigned short* wt2h       = (unsigned short*)take(64 * 128 * 2);
    unsigned short* wt2l       = (unsigned short*)take(64 * 128 * 2);
    unsigned int*   h          = (unsigned int*)take((size_t)N * 64 * 4);  // bf16 h' (128 feats)
    float*          z          = (float*)take((size_t)N * F1 * 4);
    unsigned int*   h2         = h;   // h dead after agg1; bf16 h2' (64 feats)
    float*          out        = (float*)d_out;

    hipMemsetAsync(bnacc, 0, 4 * 256 * 8, stream);

    const int eb = (E + CHUNK - 1) / CHUNK;

    wprep_k<<<14, 256, 0, stream>>>(W1, W2, wt1h, wt1l, wt2h, wt2l, bucketcur);
    binpass_k<<<eb, 256, 0, stream>>>(src, dst, bucketcur, pairs, E);
    bucket_k<<<NBUCK, 256, 0, stream>>>(pairs, bucketcur, dinv, rowptr, rowend, srcsorted, N);

    gemm1_k<<<(N + 127) / 128, 512, 0, stream>>>(x, wt1h, wt1l, dinv, h, N);
    agg1_k<<<N, 64, 0, stream>>>(h, dinv, rowptr, rowend, srcsorted, b1, z, N);
    bnstats_k<<<1024, 256, 0, stream>>>(z, bnacc, N);
    gemm2_k<<<(N + 127) / 128, 512, 0, stream>>>(z, wt2h, wt2l, bnacc, gamma, beta, prelu_a, dinv, h2, N);
    agg2_k<<<N, F2, 0, stream>>>((const unsigned short*)h2, dinv, rowptr, rowend, srcsorted, b2, out, N);
}